// Round 15
// baseline (195.557 us; speedup 1.0000x reference)
//
#include <hip/hip_runtime.h>
#include <math.h>

#define BATCH 4
#define SEQ   1024
#define DIM_C 1024
#define HEADS 16
#define HDIM  64
#define F3    3072

typedef short bf8 __attribute__((ext_vector_type(8)));
typedef float f32x4 __attribute__((ext_vector_type(4)));

__device__ __forceinline__ ushort f2bf(float f) {
    union { float f; unsigned u; } c; c.f = f;
    unsigned u = c.u + 0x7fffu + ((c.u >> 16) & 1u);
    return (ushort)(u >> 16);
}
__device__ __forceinline__ float bf2f(ushort s) {
    union { unsigned u; float f; } c; c.u = ((unsigned)s) << 16;
    return c.f;
}

// async 16B global -> LDS (wave-uniform LDS base; lane*16 is implicit)
__device__ __forceinline__ void stage16(const ushort* g, ushort* l) {
    __builtin_amdgcn_global_load_lds(
        (const __attribute__((address_space(1))) unsigned int*)g,
        (__attribute__((address_space(3))) unsigned int*)l, 16, 0, 0);
}

// ---------------------------------------------------------------------------
// fp32 -> bf16 bulk convert of all four inputs in one launch.
// ---------------------------------------------------------------------------
__global__ __launch_bounds__(256) void cvt_all_kernel(
    const float* __restrict__ x, const float* __restrict__ wqkv,
    const float* __restrict__ wproj, const float* __restrict__ er,
    ushort* __restrict__ xb, ushort* __restrict__ wqkvb,
    ushort* __restrict__ wprojb, ushort* __restrict__ erb)
{
    const int blk = blockIdx.x;
    const float* src; ushort* dst; size_t off;
    if (blk < 2048)      { src = x;     dst = xb;     off = (size_t)blk * 2048; }
    else if (blk < 3584) { src = wqkv;  dst = wqkvb;  off = (size_t)(blk - 2048) * 2048; }
    else if (blk < 4096) { src = wproj; dst = wprojb; off = (size_t)(blk - 3584) * 2048; }
    else                 { src = er;    dst = erb;    off = (size_t)(blk - 4096) * 2048; }
    size_t i = off + (size_t)threadIdx.x * 8;
    float4 v0 = *(const float4*)&src[i];
    float4 v1 = *(const float4*)&src[i + 4];
    ushort o[8];
    o[0] = f2bf(v0.x); o[1] = f2bf(v0.y); o[2] = f2bf(v0.z); o[3] = f2bf(v0.w);
    o[4] = f2bf(v1.x); o[5] = f2bf(v1.y); o[6] = f2bf(v1.z); o[7] = f2bf(v1.w);
    *(uint4*)&dst[i] = *(uint4*)o;
}

// ---------------------------------------------------------------------------
// SWIZZLED m97-style core (r13, verified on qkv: SQ_LDS_BANK_CONFLICT 0,
// qkv 47.8us). Used by gemm_qkv only. NO __launch_bounds__ cap (r12 lesson:
// capping below the ~105-VGPR accumulator floor spills -> 5.7x regression).
// ---------------------------------------------------------------------------
__device__ __forceinline__ void gemm_core_sw(
    const ushort* __restrict__ a, const ushort* __restrict__ b,
    ushort* As, ushort* Bs, int m0, int f0, int t, f32x4 (&acc)[4][4])
{
    const int lane = t & 63, w = t >> 6;
    const int lc = lane & 15, g4 = lane >> 4;
    const int wm = (w >> 1) * 64, wn = (w & 1) * 64;
    const int rowS = w * 32 + (lane >> 2);
    const int kkS  = ((lane & 3) ^ ((rowS >> 1) & 3)) * 8;
    const int coff = (g4 ^ ((lc >> 1) & 3)) * 8;

    for (int kt = 0; kt < 32; ++kt) {
        const int k0 = kt * 32;
        __syncthreads();
        #pragma unroll
        for (int ii = 0; ii < 2; ++ii) {
            stage16(&a[(size_t)(m0 + rowS + ii * 16) * 1024 + k0 + kkS],
                    &As[(w * 2 + ii) * 512]);
            stage16(&b[(size_t)(f0 + rowS + ii * 16) * 1024 + k0 + kkS],
                    &Bs[(w * 2 + ii) * 512]);
        }
        __syncthreads();
        bf8 af[4], bfr[4];
        #pragma unroll
        for (int mb = 0; mb < 4; ++mb)
            af[mb] = *(const bf8*)&As[(wm + mb * 16 + lc) * 32 + coff];
        #pragma unroll
        for (int nb = 0; nb < 4; ++nb)
            bfr[nb] = *(const bf8*)&Bs[(wn + nb * 16 + lc) * 32 + coff];
        #pragma unroll
        for (int mb = 0; mb < 4; ++mb)
            #pragma unroll
            for (int nb = 0; nb < 4; ++nb)
                acc[mb][nb] = __builtin_amdgcn_mfma_f32_16x16x32_bf16(
                    af[mb], bfr[nb], acc[mb][nb], 0, 0, 0);
    }
}

// ---------------------------------------------------------------------------
// NON-SWIZZLED core (r10 original) for gemm_proj. proj runs 1 block/CU
// (grid 256) where LDS bank conflicts are latency-hidden; the swizzle's
// +32 VGPR / extra address math is pure cost there. A/B: r10 (proj on this
// core) total 187.3 vs r11/r13/r14 (proj on swizzle core) 193.5-194.4 with
// an ~11us rest-of-pipeline hole pointing at proj.
// ---------------------------------------------------------------------------
__device__ __forceinline__ void gemm_core_ns(
    const ushort* __restrict__ a, const ushort* __restrict__ b,
    ushort* As, ushort* Bs, int m0, int f0, int t, f32x4 (&acc)[4][4])
{
    const int lane = t & 63, w = t >> 6;
    const int lc = lane & 15, g4 = lane >> 4;
    const int wm = (w >> 1) * 64, wn = (w & 1) * 64;
    const int rowS = w * 32 + (lane >> 2);
    const int kkS  = (lane & 3) * 8;

    for (int kt = 0; kt < 32; ++kt) {
        const int k0 = kt * 32;
        __syncthreads();
        #pragma unroll
        for (int ii = 0; ii < 2; ++ii) {
            stage16(&a[(size_t)(m0 + rowS + ii * 16) * 1024 + k0 + kkS],
                    &As[(w * 2 + ii) * 512]);
            stage16(&b[(size_t)(f0 + rowS + ii * 16) * 1024 + k0 + kkS],
                    &Bs[(w * 2 + ii) * 512]);
        }
        __syncthreads();
        bf8 af[4], bfr[4];
        #pragma unroll
        for (int mb = 0; mb < 4; ++mb)
            af[mb] = *(const bf8*)&As[(wm + mb * 16 + lc) * 32 + g4 * 8];
        #pragma unroll
        for (int nb = 0; nb < 4; ++nb)
            bfr[nb] = *(const bf8*)&Bs[(wn + nb * 16 + lc) * 32 + g4 * 8];
        #pragma unroll
        for (int mb = 0; mb < 4; ++mb)
            #pragma unroll
            for (int nb = 0; nb < 4; ++nb)
                acc[mb][nb] = __builtin_amdgcn_mfma_f32_16x16x32_bf16(
                    af[mb], bfr[nb], acc[mb][nb], 0, 0, 0);
    }
}

// qkv: q,k written [b,h,n,d]. V: operand-swapped GEMM (A=W_v rows, B=x) so
// V^T stores are coalesced (WRITE_SIZE 44.5 -> 24.6 MB, verified r11).
__global__ __launch_bounds__(256) void gemm_qkv_mfma(
    const ushort* __restrict__ xb, const ushort* __restrict__ wb,
    ushort* __restrict__ qp, ushort* __restrict__ kp, ushort* __restrict__ vp)
{
    __shared__ __align__(16) ushort As[128 * 32];
    __shared__ __align__(16) ushort Bs[128 * 32];
    const int t = threadIdx.x;
    const int bx = blockIdx.x, by = blockIdx.y;
    const bool isV = (bx >= 16);
    const int m0 = isV ? 2048 + (bx - 16) * 128 : by * 128;
    const int f0 = isV ? by * 128 : bx * 128;
    const ushort* A = isV ? wb : xb;
    const ushort* B = isV ? xb : wb;

    f32x4 acc[4][4];
    #pragma unroll
    for (int mb = 0; mb < 4; ++mb)
        #pragma unroll
        for (int nb = 0; nb < 4; ++nb) acc[mb][nb] = (f32x4){0.f, 0.f, 0.f, 0.f};

    gemm_core_sw(A, B, As, Bs, m0, f0, t, acc);

    const int lane = t & 63, w = t >> 6;
    const int lc = lane & 15, g4 = lane >> 4;
    const int wm = (w >> 1) * 64, wn = (w & 1) * 64;
    if (isV) {
        #pragma unroll
        for (int mb = 0; mb < 4; ++mb)
            #pragma unroll
            for (int nb = 0; nb < 4; ++nb) {
                const int ncol = f0 + wn + nb * 16 + lc;
                const int bi = ncol >> 10, nl = ncol & 1023;
                #pragma unroll
                for (int i = 0; i < 4; ++i) {
                    const int vrow = m0 + wm + mb * 16 + g4 * 4 + i - 2048;
                    const int h = vrow >> 6, d = vrow & 63;
                    vp[(((size_t)(bi * 16 + h)) * 64 + d) * 1024 + nl] = f2bf(acc[mb][nb][i]);
                }
            }
    } else {
        const int s = f0 >> 10;                  // uniform: 0=q 1=k
        ushort* dst = (s == 0) ? qp : kp;
        #pragma unroll
        for (int mb = 0; mb < 4; ++mb)
            #pragma unroll
            for (int nb = 0; nb < 4; ++nb) {
                const int f = f0 + wn + nb * 16 + lc;
                const int h = (f >> 6) & 15, d = f & 63;
                #pragma unroll
                for (int i = 0; i < 4; ++i) {
                    const int m = m0 + wm + mb * 16 + g4 * 4 + i;
                    const int b = m >> 10, n = m & 1023;
                    dst[(((size_t)(b * 16 + h)) * 1024 + n) * 64 + d] = f2bf(acc[mb][nb][i]);
                }
            }
    }
}

// proj: +bias, fp32 out — on the NON-swizzled r10 core (see gemm_core_ns).
__global__ __launch_bounds__(256) void gemm_proj_mfma(
    const ushort* __restrict__ ab, const ushort* __restrict__ wb,
    const float* __restrict__ bias, float* __restrict__ y)
{
    __shared__ __align__(16) ushort As[128 * 32];
    __shared__ __align__(16) ushort Bs[128 * 32];
    const int t = threadIdx.x;
    const int m0 = blockIdx.y * 128, f0 = blockIdx.x * 128;
    f32x4 acc[4][4];
    #pragma unroll
    for (int mb = 0; mb < 4; ++mb)
        #pragma unroll
        for (int nb = 0; nb < 4; ++nb) acc[mb][nb] = (f32x4){0.f, 0.f, 0.f, 0.f};

    gemm_core_ns(ab, wb, As, Bs, m0, f0, t, acc);

    const int lane = t & 63, w = t >> 6;
    const int lc = lane & 15, g4 = lane >> 4;
    const int wm = (w >> 1) * 64, wn = (w & 1) * 64;
    #pragma unroll
    for (int mb = 0; mb < 4; ++mb)
        #pragma unroll
        for (int nb = 0; nb < 4; ++nb) {
            const int f = f0 + wn + nb * 16 + lc;
            const float bv = bias[f];
            #pragma unroll
            for (int i = 0; i < 4; ++i) {
                const int m = m0 + wm + mb * 16 + g4 * 4 + i;
                y[(size_t)m * 1024 + f] = acc[mb][nb][i] + bv;
            }
        }
}

// ---------------------------------------------------------------------------
// Split-K MFMA flash attention (round-10 winner, unchanged): QBLK=128,
// 8 waves/block, shared K/V/Er staging, r9 in-register rel-skew shuffle.
// ---------------------------------------------------------------------------
__global__ __launch_bounds__(512, 4) void attn_mfma_kernel(
    const ushort* __restrict__ qg, const ushort* __restrict__ kg,
    const ushort* __restrict__ vtg, const ushort* __restrict__ erg,
    ushort* __restrict__ pOd, float* __restrict__ pL)
{
    __shared__ __align__(16) ushort k_s[2][64][64];
    __shared__ __align__(16) ushort vt_s[2][64][64];
    __shared__ __align__(16) ushort e_s[4][64][64];
    __shared__ __align__(16) ushort p_s[8][16][64];

    const int t = threadIdx.x;
    const int w = t >> 6, lane = t & 63;
    const int lc = lane & 15, g4 = lane >> 4;
    const int b = blockIdx.z, h = blockIdx.y;
    const int u = blockIdx.x;                     // 0..19
    const int cum[9] = {0, 1, 2, 4, 6, 9, 12, 16, 20};
    int bx = 0;
    #pragma unroll
    for (int j = 1; j < 8; ++j) if (u >= cum[j]) bx = j;
    const int part = u - cum[bx];
    const int t0 = part * 4;
    const int t1 = min(t0 + 4, 2 * bx + 2);

    const int n0 = bx * 128;
    const int n0w = n0 + w * 16;                  // this wave's 16 q-rows
    const int ch0 = 14 + t0 - 2 * bx;             // first Er chunk of window

    const ushort* qb  = qg  + ((size_t)(b * 16 + h)) * 65536;
    const ushort* kb  = kg  + ((size_t)(b * 16 + h)) * 65536;
    const ushort* vtb = vtg + ((size_t)(b * 16 + h)) * 65536;  // [d][n]

    // staging lane geometry: 64 lanes x 16B = 8 rows of 128B, XOR-swizzled cols
    const int srow = lane >> 3;                   // 0..7
    const int scol = ((lane & 7) ^ srow) * 8;
    const int sr0  = w * 8 + srow;                // wave stages 8 rows
    const int rsw  = (lc & 7) * 8;

    // prologue: stage tile t0 K/V^T into buf 0, Er chunks ch0..ch0+2
    stage16(&kb[(size_t)(t0 * 64 + sr0) * 64 + scol], &k_s[0][w * 8][0]);
    stage16(&vtb[(size_t)sr0 * 1024 + t0 * 64 + scol], &vt_s[0][w * 8][0]);
    #pragma unroll
    for (int cc = 0; cc < 3; ++cc) {
        const int ch = ch0 + cc;
        int gr = ch * 64 + sr0;
        gr = (gr > 1023) ? 1023 : gr;   // clamped rows feed masked entries
        stage16(&erg[(size_t)gr * 64 + scol], &e_s[ch & 3][w * 8][0]);
    }

    bf8 qf[2];
    #pragma unroll
    for (int c = 0; c < 2; ++c)
        qf[c] = *(const bf8*)&qb[(size_t)(n0w + lc) * 64 + c * 32 + g4 * 8];

    asm volatile("s_waitcnt vmcnt(0)" ::: "memory");
    __builtin_amdgcn_s_barrier();

    const f32x4 z4 = {0.f, 0.f, 0.f, 0.f};
    f32x4 od[4] = {z4, z4, z4, z4};
    float lrow[4] = {0.f, 0.f, 0.f, 0.f};
    int cur = 0;

    for (int tt = t0; tt < t1; ++tt) {
        const int m0 = tt * 64;

        if (tt + 1 < t1) {
            const int m1 = m0 + 64;
            const int nxt = cur ^ 1;
            stage16(&kb[(size_t)(m1 + sr0) * 64 + scol], &k_s[nxt][w * 8][0]);
            stage16(&vtb[(size_t)sr0 * 1024 + m1 + scol], &vt_s[nxt][w * 8][0]);
            const int chN = 17 + tt - 2 * bx;     // prefetch chunk
            int gr = chN * 64 + sr0;
            gr = (gr > 1023) ? 1023 : gr;
            stage16(&erg[(size_t)gr * 64 + scol], &e_s[chN & 3][w * 8][0]);
            // outstanding: cur tile's 3 (old) + next tile's 3 (new)
            asm volatile("s_waitcnt vmcnt(3)" ::: "memory");
        } else {
            asm volatile("s_waitcnt vmcnt(0)" ::: "memory");
        }
        __builtin_amdgcn_s_barrier();

        // content scores S[16][64]
        f32x4 sc[4] = {z4, z4, z4, z4};
        #pragma unroll
        for (int jt = 0; jt < 4; ++jt)
            #pragma unroll
            for (int c = 0; c < 2; ++c) {
                bf8 kf = *(const bf8*)&k_s[cur][jt * 16 + lc][((c * 4 + g4) * 8) ^ rsw];
                sc[jt] = __builtin_amdgcn_mfma_f32_16x16x32_bf16(qf[c], kf, sc[jt], 0, 0, 0);
            }

        // rel tile R[16][80]; Er rows eBw..eBw+79 (Er row = 1023+m-n)
        const int eBw = 1008 + m0 - n0 - 16 * w;
        f32x4 rc[5] = {z4, z4, z4, z4, z4};
        #pragma unroll
        for (int jr = 0; jr < 5; ++jr) {
            const int g  = eBw + jr * 16 + lc;        // global Er row (logical)
            const int s3 = (g >> 6) & 3;
            const int r  = g & 63;                    // r & 7 == lc & 7
            #pragma unroll
            for (int c = 0; c < 2; ++c) {
                bf8 ef = *(const bf8*)&e_s[s3][r][((c * 4 + g4) * 8) ^ rsw];
                rc[jr] = __builtin_amdgcn_mfma_f32_16x16x32_bf16(qf[c], ef, rc[jr], 0, 0, 0);
            }
        }

        // p = exp((sc+rel)/8), masked; rel gathered via 16-wide shuffles;
        // P -> p_s with XOR-block swizzle (store blk ^ (row&7))
        #pragma unroll
        for (int i = 0; i < 4; ++i) {
            const int row = g4 * 4 + i;
            const int n = n0w + row;
            const int src = (lc + 15 - row) & 15;
            float sh[5];
            #pragma unroll
            for (int jr = 0; jr < 5; ++jr)
                sh[jr] = __shfl(rc[jr][i], src, 16);
            #pragma unroll
            for (int jt = 0; jt < 4; ++jt) {
                const float rel = (lc > row) ? sh[jt + 1] : sh[jt];
                const float s = (sc[jt][i] + rel) * 0.125f;
                const int m = m0 + jt * 16 + lc;
                const float p = (m <= n) ? __expf(s) : 0.f;
                const int blk = (jt * 2 + (lc >> 3)) ^ (row & 7);
                p_s[w][row][blk * 8 + (lc & 7)] = f2bf(p);
                lrow[i] += p;
            }
        }
        asm volatile("s_waitcnt lgkmcnt(0)" ::: "memory");

        // PV: A = P (A-layout, de-swizzled read), B = V^T from LDS
        bf8 pf[2];
        #pragma unroll
        for (int c = 0; c < 2; ++c)
            pf[c] = *(const bf8*)&p_s[w][lc][((c * 4 + g4) ^ (lc & 7)) * 8];
        #pragma unroll
        for (int dt = 0; dt < 4; ++dt)
            #pragma unroll
            for (int c = 0; c < 2; ++c) {
                bf8 vf = *(const bf8*)&vt_s[cur][dt * 16 + lc][((c * 4 + g4) * 8) ^ rsw];
                od[dt] = __builtin_amdgcn_mfma_f32_16x16x32_bf16(pf[c], vf, od[dt], 0, 0, 0);
            }

        __builtin_amdgcn_s_barrier();   // cur reads done before next overwrite
        cur ^= 1;
    }

    // epilogue: reduce l over the 16 lc lanes; write unnormalized partials
    #pragma unroll
    for (int off = 1; off < 16; off <<= 1)
        #pragma unroll
        for (int i = 0; i < 4; ++i)
            lrow[i] += __shfl_xor(lrow[i], off, 16);

    const size_t pbase = (size_t)((b * 16 + h) * 20 + u);
    #pragma unroll
    for (int i = 0; i < 4; ++i) {
        const int nl = w * 16 + g4 * 4 + i;       // 0..127
        #pragma unroll
        for (int dt = 0; dt < 4; ++dt)
            pOd[pbase * 8192 + nl * 64 + dt * 16 + lc] = f2bf(od[dt][i]);
        if (lc == 0) pL[pbase * 128 + nl] = lrow[i];
    }
}

// ---------------------------------------------------------------------------
// Combine: sum <=4 partials per (bh, 128-row n-chunk), normalize, write attnb.
// ---------------------------------------------------------------------------
__global__ __launch_bounds__(256) void attn_combine_kernel(
    const ushort* __restrict__ pOd, const float* __restrict__ pL,
    ushort* __restrict__ attnb)
{
    const int tid = blockIdx.x * 256 + threadIdx.x;
    const int d8 = tid & 7;
    const int n  = (tid >> 3) & 1023;
    const int bh = tid >> 13;
    const int bx = n >> 7, nl = n & 127;
    const int cum[9] = {0, 1, 2, 4, 6, 9, 12, 16, 20};
    const int u0 = cum[bx], pc = cum[bx + 1] - cum[bx];

    float acc[8] = {0.f, 0.f, 0.f, 0.f, 0.f, 0.f, 0.f, 0.f};
    float lsum = 0.f;
    for (int j = 0; j < pc; ++j) {
        const size_t base = (size_t)(bh * 20 + u0 + j);
        uint4 pv = *(const uint4*)&pOd[base * 8192 + nl * 64 + d8 * 8];
        const ushort* pp = (const ushort*)&pv;
        #pragma unroll
        for (int e = 0; e < 8; ++e) acc[e] += bf2f(pp[e]);
        lsum += pL[base * 128 + nl];
    }
    const float inv = 1.f / lsum;
    ushort o[8];
    #pragma unroll
    for (int e = 0; e < 8; ++e) o[e] = f2bf(acc[e] * inv);
    const int b = bh >> 4, h = bh & 15;
    *(uint4*)&attnb[((size_t)(b * 1024) + n) * 1024 + h * 64 + d8 * 8] = *(uint4*)o;
}

// ---------------------------------------------------------------------------
extern "C" void kernel_launch(void* const* d_in, const int* in_sizes, int n_in,
                              void* d_out, int out_size, void* d_ws, size_t ws_size,
                              hipStream_t stream)
{
    const float* x     = (const float*)d_in[0];
    const float* Wqkv  = (const float*)d_in[1];
    const float* Wproj = (const float*)d_in[2];
    const float* bproj = (const float*)d_in[3];
    const float* Er    = (const float*)d_in[4];
    float* out = (float*)d_out;

    const size_t per = (size_t)BATCH * HEADS * SEQ * HDIM;   // 4,194,304
    ushort* xb     = (ushort*)d_ws;
    ushort* wqkvb  = xb + (size_t)4194304;
    ushort* wprojb = wqkvb + (size_t)3145728;
    ushort* erb    = wprojb + (size_t)1048576;
    ushort* qw     = erb + (size_t)65536;
    ushort* kw     = qw + per;
    ushort* vw     = kw + per;      // V^T: [b,h,d,n]
    ushort* attnb  = vw + per;
    ushort* pOd    = attnb + per;   // 64 bh x 20 u x 8192 bf16 = 21 MB
    float*  pL     = (float*)(pOd + (size_t)64 * 20 * 8192);  // 64*20*128 f32

    cvt_all_kernel<<<dim3(4128), 256, 0, stream>>>(
        x, Wqkv, Wproj, Er, xb, wqkvb, wprojb, erb);

    gemm_qkv_mfma<<<dim3(F3 / 128, (BATCH * SEQ) / 128), 256, 0, stream>>>(
        xb, wqkvb, qw, kw, vw);

    attn_mfma_kernel<<<dim3(20, HEADS, BATCH), 512, 0, stream>>>(
        qw, kw, vw, erb, pOd, pL);

    attn_combine_kernel<<<dim3(2048), 256, 0, stream>>>(pOd, pL, attnb);

    gemm_proj_mfma<<<dim3(DIM_C / 128, (BATCH * SEQ) / 128), 256, 0, stream>>>(
        attnb, wprojb, bproj, out);
}

// Round 16
// 186.201 us; speedup vs baseline: 1.0502x; 1.0502x over previous
//
#include <hip/hip_runtime.h>
#include <math.h>

#define BATCH 4
#define SEQ   1024
#define DIM_C 1024
#define HEADS 16
#define HDIM  64
#define F3    3072

typedef short bf8 __attribute__((ext_vector_type(8)));
typedef float f32x4 __attribute__((ext_vector_type(4)));

__device__ __forceinline__ ushort f2bf(float f) {
    union { float f; unsigned u; } c; c.f = f;
    unsigned u = c.u + 0x7fffu + ((c.u >> 16) & 1u);
    return (ushort)(u >> 16);
}
__device__ __forceinline__ float bf2f(ushort s) {
    union { unsigned u; float f; } c; c.u = ((unsigned)s) << 16;
    return c.f;
}

// async 16B global -> LDS (wave-uniform LDS base; lane*16 is implicit)
__device__ __forceinline__ void stage16(const ushort* g, ushort* l) {
    __builtin_amdgcn_global_load_lds(
        (const __attribute__((address_space(1))) unsigned int*)g,
        (__attribute__((address_space(3))) unsigned int*)l, 16, 0, 0);
}

// ---------------------------------------------------------------------------
// fp32 -> bf16 bulk convert of all four inputs in one launch.
// ---------------------------------------------------------------------------
__global__ __launch_bounds__(256) void cvt_all_kernel(
    const float* __restrict__ x, const float* __restrict__ wqkv,
    const float* __restrict__ wproj, const float* __restrict__ er,
    ushort* __restrict__ xb, ushort* __restrict__ wqkvb,
    ushort* __restrict__ wprojb, ushort* __restrict__ erb)
{
    const int blk = blockIdx.x;
    const float* src; ushort* dst; size_t off;
    if (blk < 2048)      { src = x;     dst = xb;     off = (size_t)blk * 2048; }
    else if (blk < 3584) { src = wqkv;  dst = wqkvb;  off = (size_t)(blk - 2048) * 2048; }
    else if (blk < 4096) { src = wproj; dst = wprojb; off = (size_t)(blk - 3584) * 2048; }
    else                 { src = er;    dst = erb;    off = (size_t)(blk - 4096) * 2048; }
    size_t i = off + (size_t)threadIdx.x * 8;
    float4 v0 = *(const float4*)&src[i];
    float4 v1 = *(const float4*)&src[i + 4];
    ushort o[8];
    o[0] = f2bf(v0.x); o[1] = f2bf(v0.y); o[2] = f2bf(v0.z); o[3] = f2bf(v0.w);
    o[4] = f2bf(v1.x); o[5] = f2bf(v1.y); o[6] = f2bf(v1.z); o[7] = f2bf(v1.w);
    *(uint4*)&dst[i] = *(uint4*)o;
}

// ---------------------------------------------------------------------------
// m97-style MFMA GEMM core (r10 configuration — A/B test: this exact config
// measured 187.3 total vs the swizzle-family's 193.5-195.6; this round
// discriminates "r10 = favorable noise" vs "r10 config genuinely better".)
// ---------------------------------------------------------------------------
__device__ __forceinline__ void gemm_core(
    const ushort* __restrict__ a, const ushort* __restrict__ b,
    ushort* As, ushort* Bs, int m0, int f0, int t, f32x4 (&acc)[4][4])
{
    const int lane = t & 63, w = t >> 6;
    const int lc = lane & 15, g4 = lane >> 4;
    const int wm = (w >> 1) * 64, wn = (w & 1) * 64;
    const int rowS = w * 32 + (lane >> 2);
    const int kkS  = (lane & 3) * 8;

    for (int kt = 0; kt < 32; ++kt) {
        const int k0 = kt * 32;
        __syncthreads();
        #pragma unroll
        for (int ii = 0; ii < 2; ++ii) {
            stage16(&a[(size_t)(m0 + rowS + ii * 16) * 1024 + k0 + kkS],
                    &As[(w * 2 + ii) * 512]);
            stage16(&b[(size_t)(f0 + rowS + ii * 16) * 1024 + k0 + kkS],
                    &Bs[(w * 2 + ii) * 512]);
        }
        __syncthreads();
        bf8 af[4], bfr[4];
        #pragma unroll
        for (int mb = 0; mb < 4; ++mb)
            af[mb] = *(const bf8*)&As[(wm + mb * 16 + lc) * 32 + g4 * 8];
        #pragma unroll
        for (int nb = 0; nb < 4; ++nb)
            bfr[nb] = *(const bf8*)&Bs[(wn + nb * 16 + lc) * 32 + g4 * 8];
        #pragma unroll
        for (int mb = 0; mb < 4; ++mb)
            #pragma unroll
            for (int nb = 0; nb < 4; ++nb)
                acc[mb][nb] = __builtin_amdgcn_mfma_f32_16x16x32_bf16(
                    af[mb], bfr[nb], acc[mb][nb], 0, 0, 0);
    }
}

// qkv: q,k written [b,h,n,d]; V written TRANSPOSED [b,h,d,n] (ushort4 stores).
__global__ __launch_bounds__(256) void gemm_qkv_mfma(
    const ushort* __restrict__ xb, const ushort* __restrict__ wb,
    ushort* __restrict__ qp, ushort* __restrict__ kp, ushort* __restrict__ vp)
{
    __shared__ __align__(16) ushort As[128 * 32];
    __shared__ __align__(16) ushort Bs[128 * 32];
    const int t = threadIdx.x;
    const int m0 = blockIdx.y * 128, f0 = blockIdx.x * 128;
    f32x4 acc[4][4];
    #pragma unroll
    for (int mb = 0; mb < 4; ++mb)
        #pragma unroll
        for (int nb = 0; nb < 4; ++nb) acc[mb][nb] = (f32x4){0.f, 0.f, 0.f, 0.f};

    gemm_core(xb, wb, As, Bs, m0, f0, t, acc);

    const int lane = t & 63, w = t >> 6;
    const int lc = lane & 15, g4 = lane >> 4;
    const int wm = (w >> 1) * 64, wn = (w & 1) * 64;
    const int s = f0 >> 10;                      // uniform: 0=q 1=k 2=v
    #pragma unroll
    for (int mb = 0; mb < 4; ++mb)
        #pragma unroll
        for (int nb = 0; nb < 4; ++nb) {
            const int f = f0 + wn + nb * 16 + lc;
            const int h = (f >> 6) & 15, d = f & 63;
            if (s == 2) {
                const int m = m0 + wm + mb * 16 + g4 * 4;
                const int b = m >> 10, n = m & 1023;
                ushort4 o;
                o.x = f2bf(acc[mb][nb][0]); o.y = f2bf(acc[mb][nb][1]);
                o.z = f2bf(acc[mb][nb][2]); o.w = f2bf(acc[mb][nb][3]);
                *(ushort4*)&vp[(((size_t)(b * 16 + h)) * 64 + d) * 1024 + n] = o;
            } else {
                ushort* dst = (s == 0) ? qp : kp;
                #pragma unroll
                for (int i = 0; i < 4; ++i) {
                    const int m = m0 + wm + mb * 16 + g4 * 4 + i;
                    const int b = m >> 10, n = m & 1023;
                    dst[(((size_t)(b * 16 + h)) * 1024 + n) * 64 + d] = f2bf(acc[mb][nb][i]);
                }
            }
        }
}

// proj: +bias, fp32 out
__global__ __launch_bounds__(256) void gemm_proj_mfma(
    const ushort* __restrict__ ab, const ushort* __restrict__ wb,
    const float* __restrict__ bias, float* __restrict__ y)
{
    __shared__ __align__(16) ushort As[128 * 32];
    __shared__ __align__(16) ushort Bs[128 * 32];
    const int t = threadIdx.x;
    const int m0 = blockIdx.y * 128, f0 = blockIdx.x * 128;
    f32x4 acc[4][4];
    #pragma unroll
    for (int mb = 0; mb < 4; ++mb)
        #pragma unroll
        for (int nb = 0; nb < 4; ++nb) acc[mb][nb] = (f32x4){0.f, 0.f, 0.f, 0.f};

    gemm_core(ab, wb, As, Bs, m0, f0, t, acc);

    const int lane = t & 63, w = t >> 6;
    const int lc = lane & 15, g4 = lane >> 4;
    const int wm = (w >> 1) * 64, wn = (w & 1) * 64;
    #pragma unroll
    for (int mb = 0; mb < 4; ++mb)
        #pragma unroll
        for (int nb = 0; nb < 4; ++nb) {
            const int f = f0 + wn + nb * 16 + lc;
            const float bv = bias[f];
            #pragma unroll
            for (int i = 0; i < 4; ++i) {
                const int m = m0 + wm + mb * 16 + g4 * 4 + i;
                y[(size_t)m * 1024 + f] = acc[mb][nb][i] + bv;
            }
        }
}

// ---------------------------------------------------------------------------
// Split-K MFMA flash attention (round-10 winner, unchanged): QBLK=128,
// 8 waves/block, shared K/V/Er staging, r9 in-register rel-skew shuffle.
// ---------------------------------------------------------------------------
__global__ __launch_bounds__(512, 4) void attn_mfma_kernel(
    const ushort* __restrict__ qg, const ushort* __restrict__ kg,
    const ushort* __restrict__ vtg, const ushort* __restrict__ erg,
    ushort* __restrict__ pOd, float* __restrict__ pL)
{
    __shared__ __align__(16) ushort k_s[2][64][64];
    __shared__ __align__(16) ushort vt_s[2][64][64];
    __shared__ __align__(16) ushort e_s[4][64][64];
    __shared__ __align__(16) ushort p_s[8][16][64];

    const int t = threadIdx.x;
    const int w = t >> 6, lane = t & 63;
    const int lc = lane & 15, g4 = lane >> 4;
    const int b = blockIdx.z, h = blockIdx.y;
    const int u = blockIdx.x;                     // 0..19
    const int cum[9] = {0, 1, 2, 4, 6, 9, 12, 16, 20};
    int bx = 0;
    #pragma unroll
    for (int j = 1; j < 8; ++j) if (u >= cum[j]) bx = j;
    const int part = u - cum[bx];
    const int t0 = part * 4;
    const int t1 = min(t0 + 4, 2 * bx + 2);

    const int n0 = bx * 128;
    const int n0w = n0 + w * 16;                  // this wave's 16 q-rows
    const int ch0 = 14 + t0 - 2 * bx;             // first Er chunk of window

    const ushort* qb  = qg  + ((size_t)(b * 16 + h)) * 65536;
    const ushort* kb  = kg  + ((size_t)(b * 16 + h)) * 65536;
    const ushort* vtb = vtg + ((size_t)(b * 16 + h)) * 65536;  // [d][n]

    // staging lane geometry: 64 lanes x 16B = 8 rows of 128B, XOR-swizzled cols
    const int srow = lane >> 3;                   // 0..7
    const int scol = ((lane & 7) ^ srow) * 8;
    const int sr0  = w * 8 + srow;                // wave stages 8 rows
    const int rsw  = (lc & 7) * 8;

    // prologue: stage tile t0 K/V^T into buf 0, Er chunks ch0..ch0+2
    stage16(&kb[(size_t)(t0 * 64 + sr0) * 64 + scol], &k_s[0][w * 8][0]);
    stage16(&vtb[(size_t)sr0 * 1024 + t0 * 64 + scol], &vt_s[0][w * 8][0]);
    #pragma unroll
    for (int cc = 0; cc < 3; ++cc) {
        const int ch = ch0 + cc;
        int gr = ch * 64 + sr0;
        gr = (gr > 1023) ? 1023 : gr;   // clamped rows feed masked entries
        stage16(&erg[(size_t)gr * 64 + scol], &e_s[ch & 3][w * 8][0]);
    }

    bf8 qf[2];
    #pragma unroll
    for (int c = 0; c < 2; ++c)
        qf[c] = *(const bf8*)&qb[(size_t)(n0w + lc) * 64 + c * 32 + g4 * 8];

    asm volatile("s_waitcnt vmcnt(0)" ::: "memory");
    __builtin_amdgcn_s_barrier();

    const f32x4 z4 = {0.f, 0.f, 0.f, 0.f};
    f32x4 od[4] = {z4, z4, z4, z4};
    float lrow[4] = {0.f, 0.f, 0.f, 0.f};
    int cur = 0;

    for (int tt = t0; tt < t1; ++tt) {
        const int m0 = tt * 64;

        if (tt + 1 < t1) {
            const int m1 = m0 + 64;
            const int nxt = cur ^ 1;
            stage16(&kb[(size_t)(m1 + sr0) * 64 + scol], &k_s[nxt][w * 8][0]);
            stage16(&vtb[(size_t)sr0 * 1024 + m1 + scol], &vt_s[nxt][w * 8][0]);
            const int chN = 17 + tt - 2 * bx;     // prefetch chunk
            int gr = chN * 64 + sr0;
            gr = (gr > 1023) ? 1023 : gr;
            stage16(&erg[(size_t)gr * 64 + scol], &e_s[chN & 3][w * 8][0]);
            // outstanding: cur tile's 3 (old) + next tile's 3 (new)
            asm volatile("s_waitcnt vmcnt(3)" ::: "memory");
        } else {
            asm volatile("s_waitcnt vmcnt(0)" ::: "memory");
        }
        __builtin_amdgcn_s_barrier();

        // content scores S[16][64]
        f32x4 sc[4] = {z4, z4, z4, z4};
        #pragma unroll
        for (int jt = 0; jt < 4; ++jt)
            #pragma unroll
            for (int c = 0; c < 2; ++c) {
                bf8 kf = *(const bf8*)&k_s[cur][jt * 16 + lc][((c * 4 + g4) * 8) ^ rsw];
                sc[jt] = __builtin_amdgcn_mfma_f32_16x16x32_bf16(qf[c], kf, sc[jt], 0, 0, 0);
            }

        // rel tile R[16][80]; Er rows eBw..eBw+79 (Er row = 1023+m-n)
        const int eBw = 1008 + m0 - n0 - 16 * w;
        f32x4 rc[5] = {z4, z4, z4, z4, z4};
        #pragma unroll
        for (int jr = 0; jr < 5; ++jr) {
            const int g  = eBw + jr * 16 + lc;        // global Er row (logical)
            const int s3 = (g >> 6) & 3;
            const int r  = g & 63;                    // r & 7 == lc & 7
            #pragma unroll
            for (int c = 0; c < 2; ++c) {
                bf8 ef = *(const bf8*)&e_s[s3][r][((c * 4 + g4) * 8) ^ rsw];
                rc[jr] = __builtin_amdgcn_mfma_f32_16x16x32_bf16(qf[c], ef, rc[jr], 0, 0, 0);
            }
        }

        // p = exp((sc+rel)/8), masked; rel gathered via 16-wide shuffles;
        // P -> p_s with XOR-block swizzle (store blk ^ (row&7))
        #pragma unroll
        for (int i = 0; i < 4; ++i) {
            const int row = g4 * 4 + i;
            const int n = n0w + row;
            const int src = (lc + 15 - row) & 15;
            float sh[5];
            #pragma unroll
            for (int jr = 0; jr < 5; ++jr)
                sh[jr] = __shfl(rc[jr][i], src, 16);
            #pragma unroll
            for (int jt = 0; jt < 4; ++jt) {
                const float rel = (lc > row) ? sh[jt + 1] : sh[jt];
                const float s = (sc[jt][i] + rel) * 0.125f;
                const int m = m0 + jt * 16 + lc;
                const float p = (m <= n) ? __expf(s) : 0.f;
                const int blk = (jt * 2 + (lc >> 3)) ^ (row & 7);
                p_s[w][row][blk * 8 + (lc & 7)] = f2bf(p);
                lrow[i] += p;
            }
        }
        asm volatile("s_waitcnt lgkmcnt(0)" ::: "memory");

        // PV: A = P (A-layout, de-swizzled read), B = V^T from LDS
        bf8 pf[2];
        #pragma unroll
        for (int c = 0; c < 2; ++c)
            pf[c] = *(const bf8*)&p_s[w][lc][((c * 4 + g4) ^ (lc & 7)) * 8];
        #pragma unroll
        for (int dt = 0; dt < 4; ++dt)
            #pragma unroll
            for (int c = 0; c < 2; ++c) {
                bf8 vf = *(const bf8*)&vt_s[cur][dt * 16 + lc][((c * 4 + g4) * 8) ^ rsw];
                od[dt] = __builtin_amdgcn_mfma_f32_16x16x32_bf16(pf[c], vf, od[dt], 0, 0, 0);
            }

        __builtin_amdgcn_s_barrier();   // cur reads done before next overwrite
        cur ^= 1;
    }

    // epilogue: reduce l over the 16 lc lanes; write unnormalized partials
    #pragma unroll
    for (int off = 1; off < 16; off <<= 1)
        #pragma unroll
        for (int i = 0; i < 4; ++i)
            lrow[i] += __shfl_xor(lrow[i], off, 16);

    const size_t pbase = (size_t)((b * 16 + h) * 20 + u);
    #pragma unroll
    for (int i = 0; i < 4; ++i) {
        const int nl = w * 16 + g4 * 4 + i;       // 0..127
        #pragma unroll
        for (int dt = 0; dt < 4; ++dt)
            pOd[pbase * 8192 + nl * 64 + dt * 16 + lc] = f2bf(od[dt][i]);
        if (lc == 0) pL[pbase * 128 + nl] = lrow[i];
    }
}

// ---------------------------------------------------------------------------
// Combine: sum <=4 partials per (bh, 128-row n-chunk), normalize, write attnb.
// ---------------------------------------------------------------------------
__global__ __launch_bounds__(256) void attn_combine_kernel(
    const ushort* __restrict__ pOd, const float* __restrict__ pL,
    ushort* __restrict__ attnb)
{
    const int tid = blockIdx.x * 256 + threadIdx.x;
    const int d8 = tid & 7;
    const int n  = (tid >> 3) & 1023;
    const int bh = tid >> 13;
    const int bx = n >> 7, nl = n & 127;
    const int cum[9] = {0, 1, 2, 4, 6, 9, 12, 16, 20};
    const int u0 = cum[bx], pc = cum[bx + 1] - cum[bx];

    float acc[8] = {0.f, 0.f, 0.f, 0.f, 0.f, 0.f, 0.f, 0.f};
    float lsum = 0.f;
    for (int j = 0; j < pc; ++j) {
        const size_t base = (size_t)(bh * 20 + u0 + j);
        uint4 pv = *(const uint4*)&pOd[base * 8192 + nl * 64 + d8 * 8];
        const ushort* pp = (const ushort*)&pv;
        #pragma unroll
        for (int e = 0; e < 8; ++e) acc[e] += bf2f(pp[e]);
        lsum += pL[base * 128 + nl];
    }
    const float inv = 1.f / lsum;
    ushort o[8];
    #pragma unroll
    for (int e = 0; e < 8; ++e) o[e] = f2bf(acc[e] * inv);
    const int b = bh >> 4, h = bh & 15;
    *(uint4*)&attnb[((size_t)(b * 1024) + n) * 1024 + h * 64 + d8 * 8] = *(uint4*)o;
}

// ---------------------------------------------------------------------------
extern "C" void kernel_launch(void* const* d_in, const int* in_sizes, int n_in,
                              void* d_out, int out_size, void* d_ws, size_t ws_size,
                              hipStream_t stream)
{
    const float* x     = (const float*)d_in[0];
    const float* Wqkv  = (const float*)d_in[1];
    const float* Wproj = (const float*)d_in[2];
    const float* bproj = (const float*)d_in[3];
    const float* Er    = (const float*)d_in[4];
    float* out = (float*)d_out;

    const size_t per = (size_t)BATCH * HEADS * SEQ * HDIM;   // 4,194,304
    ushort* xb     = (ushort*)d_ws;
    ushort* wqkvb  = xb + (size_t)4194304;
    ushort* wprojb = wqkvb + (size_t)3145728;
    ushort* erb    = wprojb + (size_t)1048576;
    ushort* qw     = erb + (size_t)65536;
    ushort* kw     = qw + per;
    ushort* vw     = kw + per;      // V^T: [b,h,d,n]
    ushort* attnb  = vw + per;
    ushort* pOd    = attnb + per;   // 64 bh x 20 u x 8192 bf16 = 21 MB
    float*  pL     = (float*)(pOd + (size_t)64 * 20 * 8192);  // 64*20*128 f32

    cvt_all_kernel<<<dim3(4128), 256, 0, stream>>>(
        x, Wqkv, Wproj, Er, xb, wqkvb, wprojb, erb);

    gemm_qkv_mfma<<<dim3(F3 / 128, (BATCH * SEQ) / 128), 256, 0, stream>>>(
        xb, wqkvb, qw, kw, vw);

    attn_mfma_kernel<<<dim3(20, HEADS, BATCH), 512, 0, stream>>>(
        qw, kw, vw, erb, pOd, pL);

    attn_combine_kernel<<<dim3(2048), 256, 0, stream>>>(pOd, pL, attnb);

    gemm_proj_mfma<<<dim3(DIM_C / 128, (BATCH * SEQ) / 128), 256, 0, stream>>>(
        attnb, wprojb, bproj, out);
}